// Round 1
// baseline (1027.219 us; speedup 1.0000x reference)
//
#include <hip/hip_runtime.h>
#include <hip/hip_bf16.h>
#include <math.h>

// Problem constants
#define C_IN   256
#define C_QK   128
#define NH     8
#define H_     96
#define W_     96
#define NQ     (H_*W_)          // 9216
#define HD     (H_/2)           // 48
#define WD     (W_/2)           // 48
#define NK     (HD*WD)          // 2304
#define DQ     (C_QK/NH)        // 16
#define DV     (C_IN/NH)        // 32
// sim scale = 1/(sqrt(C_QK/NH)*temp) = 1/4
#define INV_SCALE 0.25f

// ---------------- maxpool 2x2 ----------------
__global__ __launch_bounds__(256) void maxpool_kernel(const float* __restrict__ x,
                                                      float* __restrict__ xp) {
    int idx = blockIdx.x * 256 + threadIdx.x;          // over 256*48*48
    if (idx >= C_IN * NK) return;
    int c = idx / NK;
    int r = idx - c * NK;
    int y = r / WD, xx = r - y * WD;
    const float* p = &x[c * NQ + (2 * y) * W_ + 2 * xx];
    float m = fmaxf(fmaxf(p[0], p[1]), fmaxf(p[W_], p[W_ + 1]));
    xp[idx] = m;
}

// ---------------- conv1x1 as GEMM: C[M,N] = W[M,K=256] * X[K=256,N] + bias ----------------
#define BM 64
#define BN 64
#define BK 16
#define AS_LD 68   // padded stride for As (keeps 16B alignment, rotates banks)

__global__ __launch_bounds__(256) void gemm_wx(const float* __restrict__ Wm,
                                               const float* __restrict__ X,
                                               const float* __restrict__ bias,
                                               float* __restrict__ C,
                                               int M, int N) {
    const int K = C_IN; // 256
    __shared__ float As[BK * AS_LD];  // As[k][m]
    __shared__ float Bs[BK * BN];     // Bs[k][n]

    int tid = threadIdx.x;
    int tn = tid & 15;        // 0..15
    int tm = tid >> 4;        // 0..15
    int m0 = tm * 4, n0 = tn * 4;
    int mBlk = blockIdx.y * BM;
    int nBlk = blockIdx.x * BN;

    float acc[4][4] = {};

    for (int k0 = 0; k0 < K; k0 += BK) {
        // W tile -> As (transposed): thread loads W[mBlk + t/4][k0 + (t%4)*4 .. +3]
        {
            int lm = tid >> 2;            // 0..63
            int lk = (tid & 3) * 4;       // 0,4,8,12
            float4 w4 = *(const float4*)&Wm[(mBlk + lm) * K + k0 + lk];
            As[(lk + 0) * AS_LD + lm] = w4.x;
            As[(lk + 1) * AS_LD + lm] = w4.y;
            As[(lk + 2) * AS_LD + lm] = w4.z;
            As[(lk + 3) * AS_LD + lm] = w4.w;
        }
        // X tile -> Bs: 16 rows x 64 cols, coalesced
        {
            int lk = tid >> 6;            // 0..3
            int ln = tid & 63;
            #pragma unroll
            for (int r = 0; r < 4; ++r) {
                Bs[(lk * 4 + r) * BN + ln] = X[(k0 + lk * 4 + r) * N + nBlk + ln];
            }
        }
        __syncthreads();
        #pragma unroll
        for (int kk = 0; kk < BK; ++kk) {
            float4 a4 = *(const float4*)&As[kk * AS_LD + m0];
            float4 b4 = *(const float4*)&Bs[kk * BN + n0];
            float a[4] = {a4.x, a4.y, a4.z, a4.w};
            float b[4] = {b4.x, b4.y, b4.z, b4.w};
            #pragma unroll
            for (int i = 0; i < 4; ++i)
                #pragma unroll
                for (int j = 0; j < 4; ++j)
                    acc[i][j] += a[i] * b[j];
        }
        __syncthreads();
    }

    #pragma unroll
    for (int i = 0; i < 4; ++i) {
        int m = mBlk + m0 + i;
        float bv = bias ? bias[m] : 0.0f;
        float4 o;
        o.x = acc[i][0] + bv;
        o.y = acc[i][1] + bv;
        o.z = acc[i][2] + bv;
        o.w = acc[i][3] + bv;
        *(float4*)&C[m * N + nBlk + n0] = o;
    }
}

// ---------------- fused attention (flash-style, fp32) ----------------
// One thread per query; K/V chunks staged in LDS; broadcast reads.
#define KCHUNK 256

__global__ __launch_bounds__(256) void attn_kernel(const float* __restrict__ q,
                                                   const float* __restrict__ k,
                                                   const float* __restrict__ v,
                                                   const float* __restrict__ x,
                                                   float* __restrict__ out) {
    __shared__ float Ks[DQ * KCHUNK];   // 16 KB
    __shared__ float Vs[DV * KCHUNK];   // 32 KB

    int h  = blockIdx.y;
    int qi = blockIdx.x * 256 + threadIdx.x;

    float qreg[DQ];
    #pragma unroll
    for (int d = 0; d < DQ; ++d)
        qreg[d] = q[(h * DQ + d) * NQ + qi] * INV_SCALE;

    float acc[DV] = {};
    float lsum = 0.0f;

    for (int c0 = 0; c0 < NK; c0 += KCHUNK) {
        __syncthreads();   // protect LDS reads of previous chunk
        // cooperative load: Ks = k[h*16 .. +15][c0 .. c0+255]  (1024 float4s, 4/thread)
        {
            int t = threadIdx.x;
            #pragma unroll
            for (int r = 0; r < 4; ++r) {
                int f  = r * 256 + t;            // 0..1023
                int d  = f >> 6;
                int c4 = f & 63;
                float4 kv = *(const float4*)&k[(h * DQ + d) * NK + c0 + c4 * 4];
                *(float4*)&Ks[d * KCHUNK + c4 * 4] = kv;
            }
            // Vs = v[h*32 .. +31][c0 .. c0+255]  (2048 float4s, 8/thread)
            #pragma unroll
            for (int r = 0; r < 8; ++r) {
                int f  = r * 256 + t;            // 0..2047
                int d  = f >> 6;
                int c4 = f & 63;
                float4 vv = *(const float4*)&v[(h * DV + d) * NK + c0 + c4 * 4];
                *(float4*)&Vs[d * KCHUNK + c4 * 4] = vv;
            }
        }
        __syncthreads();

        // process this chunk, 4 keys at a time
        #pragma unroll 1
        for (int kk = 0; kk < KCHUNK; kk += 4) {
            float p0 = 0.f, p1 = 0.f, p2 = 0.f, p3 = 0.f;
            #pragma unroll
            for (int d = 0; d < DQ; ++d) {
                float4 k4 = *(const float4*)&Ks[d * KCHUNK + kk];
                p0 += qreg[d] * k4.x;
                p1 += qreg[d] * k4.y;
                p2 += qreg[d] * k4.z;
                p3 += qreg[d] * k4.w;
            }
            // |sim| is small (<~2): exp without max-subtraction is exact-equivalent
            float e0 = __expf(p0), e1 = __expf(p1), e2 = __expf(p2), e3 = __expf(p3);
            lsum += (e0 + e1) + (e2 + e3);
            #pragma unroll
            for (int c = 0; c < DV; ++c) {
                float4 v4 = *(const float4*)&Vs[c * KCHUNK + kk];
                acc[c] += e0 * v4.x + e1 * v4.y + e2 * v4.z + e3 * v4.w;
            }
        }
    }

    float inv = 1.0f / lsum;
    #pragma unroll
    for (int c = 0; c < DV; ++c) {
        int row = h * DV + c;
        out[row * NQ + qi] = acc[c] * inv + x[row * NQ + qi];
    }
}

// ---------------- launcher ----------------
extern "C" void kernel_launch(void* const* d_in, const int* in_sizes, int n_in,
                              void* d_out, int out_size, void* d_ws, size_t ws_size,
                              hipStream_t stream) {
    const float* x   = (const float*)d_in[0];   // [256, 9216]
    const float* w_q = (const float*)d_in[1];   // [128, 256]
    const float* b_q = (const float*)d_in[2];   // [128]
    const float* w_k = (const float*)d_in[3];   // [128, 256]
    const float* b_k = (const float*)d_in[4];   // [128]
    const float* w_v = (const float*)d_in[5];   // [256, 256]
    float* out = (float*)d_out;                 // [256, 9216]

    // workspace layout (floats)
    float* ws = (float*)d_ws;
    float* xp   = ws;                               // 256*2304 = 589824
    float* qbuf = xp + (size_t)C_IN * NK;           // 128*9216 = 1179648
    float* kbuf = qbuf + (size_t)C_QK * NQ;         // 128*2304 = 294912
    float* vbuf = kbuf + (size_t)C_QK * NK;         // 256*2304 = 589824

    // 1) maxpool
    {
        int n = C_IN * NK;
        maxpool_kernel<<<(n + 255) / 256, 256, 0, stream>>>(x, xp);
    }
    // 2) q = w_q * x + b_q       [128, 9216]
    {
        dim3 grid(NQ / BN, C_QK / BM);
        gemm_wx<<<grid, 256, 0, stream>>>(w_q, x, b_q, qbuf, C_QK, NQ);
    }
    // 3) k = w_k * xp + b_k      [128, 2304]
    {
        dim3 grid(NK / BN, C_QK / BM);
        gemm_wx<<<grid, 256, 0, stream>>>(w_k, xp, b_k, kbuf, C_QK, NK);
    }
    // 4) v = w_v * xp            [256, 2304]
    {
        dim3 grid(NK / BN, C_IN / BM);
        gemm_wx<<<grid, 256, 0, stream>>>(w_v, xp, nullptr, vbuf, C_IN, NK);
    }
    // 5) fused attention + residual
    {
        dim3 grid(NQ / 256, NH);
        attn_kernel<<<grid, 256, 0, stream>>>(qbuf, kbuf, vbuf, x, out);
    }
}

// Round 2
// 195.207 us; speedup vs baseline: 5.2622x; 5.2622x over previous
//
#include <hip/hip_runtime.h>
#include <hip/hip_bf16.h>
#include <math.h>

// Problem constants
#define C_IN   256
#define C_QK   128
#define NH     8
#define H_     96
#define W_     96
#define NQ     (H_*W_)          // 9216
#define HD     (H_/2)           // 48
#define WD     (W_/2)           // 48
#define NK     (HD*WD)          // 2304
#define DQ     16               // C_QK/NH
#define DV     32               // C_IN/NH
#define INV_SCALE 0.25f         // 1/(sqrt(C_QK/NH)*temp)

typedef __attribute__((ext_vector_type(8))) short short8v;
typedef __attribute__((ext_vector_type(4))) float f32x4;

static __device__ inline ushort bf16r(float f) {
    __hip_bfloat16 h = __float2bfloat16(f);
    return *reinterpret_cast<ushort*>(&h);
}
static __device__ inline uint pack2(float lo, float hi) {
    return (uint)bf16r(lo) | ((uint)bf16r(hi) << 16);
}

// ---------------- maxpool 2x2 ----------------
__global__ __launch_bounds__(256) void maxpool_kernel(const float* __restrict__ x,
                                                      float* __restrict__ xp) {
    int idx = blockIdx.x * 256 + threadIdx.x;
    if (idx >= C_IN * NK) return;
    int c = idx / NK;
    int r = idx - c * NK;
    int y = r / WD, xx = r - y * WD;
    const float* p = &x[c * NQ + (2 * y) * W_ + 2 * xx];
    float m = fmaxf(fmaxf(p[0], p[1]), fmaxf(p[W_], p[W_ + 1]));
    xp[idx] = m;
}

// -------- conv1x1 GEMM (fp32 compute, bf16 out): C[M,N] = W[M,256]*X[256,N]+b --------
#define BM 64
#define BN 64
#define BK 16
#define AS_LD 68

__global__ __launch_bounds__(256) void gemm_wx_bf16(const float* __restrict__ Wm,
                                                    const float* __restrict__ X,
                                                    const float* __restrict__ bias,
                                                    ushort* __restrict__ C,
                                                    int M, int N) {
    const int K = C_IN;
    __shared__ float As[BK * AS_LD];  // As[k][m]
    __shared__ float Bs[BK * BN];     // Bs[k][n]

    int tid = threadIdx.x;
    int tn = tid & 15;
    int tm = tid >> 4;
    int m0 = tm * 4, n0 = tn * 4;
    int mBlk = blockIdx.y * BM;
    int nBlk = blockIdx.x * BN;

    float acc[4][4] = {};

    for (int k0 = 0; k0 < K; k0 += BK) {
        {
            int lm = tid >> 2;
            int lk = (tid & 3) * 4;
            float4 w4 = *(const float4*)&Wm[(mBlk + lm) * K + k0 + lk];
            As[(lk + 0) * AS_LD + lm] = w4.x;
            As[(lk + 1) * AS_LD + lm] = w4.y;
            As[(lk + 2) * AS_LD + lm] = w4.z;
            As[(lk + 3) * AS_LD + lm] = w4.w;
        }
        {
            int lk = tid >> 6;
            int ln = tid & 63;
            #pragma unroll
            for (int r = 0; r < 4; ++r)
                Bs[(lk * 4 + r) * BN + ln] = X[(size_t)(k0 + lk * 4 + r) * N + nBlk + ln];
        }
        __syncthreads();
        #pragma unroll
        for (int kk = 0; kk < BK; ++kk) {
            float4 a4 = *(const float4*)&As[kk * AS_LD + m0];
            float4 b4 = *(const float4*)&Bs[kk * BN + n0];
            float a[4] = {a4.x, a4.y, a4.z, a4.w};
            float b[4] = {b4.x, b4.y, b4.z, b4.w};
            #pragma unroll
            for (int i = 0; i < 4; ++i)
                #pragma unroll
                for (int j = 0; j < 4; ++j)
                    acc[i][j] += a[i] * b[j];
        }
        __syncthreads();
    }

    #pragma unroll
    for (int i = 0; i < 4; ++i) {
        int m = mBlk + m0 + i;
        float bv = bias ? bias[m] : 0.0f;
        ushort4 o;
        o.x = bf16r(acc[i][0] + bv);
        o.y = bf16r(acc[i][1] + bv);
        o.z = bf16r(acc[i][2] + bv);
        o.w = bf16r(acc[i][3] + bv);
        *(ushort4*)&C[(size_t)m * N + nBlk + n0] = o;
    }
}

// -------- pack K [128][2304] bf16 -> K^T [8][2304][32] bf16 (d=16..31 zero) --------
__global__ __launch_bounds__(256) void kpack_kernel(const ushort* __restrict__ kb,
                                                    ushort* __restrict__ kT) {
    int idx = blockIdx.x * 256 + threadIdx.x;   // over 8*2304
    if (idx >= NH * NK) return;
    int h = idx / NK, kk = idx - h * NK;
    union { ushort s[32]; uint4 v[4]; } t;
    #pragma unroll
    for (int d = 0; d < 16; ++d) t.s[d] = kb[(size_t)(h * 16 + d) * NK + kk];
    #pragma unroll
    for (int d = 16; d < 32; ++d) t.s[d] = 0;
    uint4* dst = (uint4*)&kT[(size_t)idx * 32];
    #pragma unroll
    for (int i = 0; i < 4; ++i) dst[i] = t.v[i];
}

// ---------------- fused attention, bf16 MFMA, flash-style ----------------
#define KB 32
#define LDSROW 40   // padded LDS row stride (bf16 elems): (5k+g)%8 spreads b128 slots

__global__ __launch_bounds__(256) void attn_mfma(const ushort* __restrict__ qb,
                                                 const ushort* __restrict__ kT,
                                                 const ushort* __restrict__ vb,
                                                 const float* __restrict__ x,
                                                 float* __restrict__ out) {
    __shared__ ushort lds[(KB + DV) * LDSROW];   // Ks[32k][40], Vs[32dv][40]

    const int h    = blockIdx.y;
    const int tid  = threadIdx.x;
    const int wv   = tid >> 6;
    const int lane = tid & 63;
    const int qcol = lane & 15;
    const int g    = lane >> 4;          // 0..3
    const bool hi  = (lane >= 32);
    const int q    = blockIdx.x * 64 + wv * 16 + qcol;

    union U8 { ushort u[8]; short8v v; };

    // Q B-frag: positional d = 8g+j, zero for d>=16 (consistent with kT padding)
    U8 qf;
    if (g < 2) {
        const ushort* qp = qb + (size_t)(h * DQ + 8 * g) * NQ + q;
        #pragma unroll
        for (int j = 0; j < 8; ++j) { qf.u[j] = *qp; qp += NQ; }
    } else {
        #pragma unroll
        for (int j = 0; j < 8; ++j) qf.u[j] = 0;
    }

    // staging assignment: tids 0..127 -> K^T chunk, 128..255 -> V chunk
    const int srow = (tid & 127) >> 2;   // 0..31
    const int sg   = tid & 3;            // 16B slot
    const ushort* sptr;
    int sstep, ldsoff;
    if (tid < 128) {
        sptr   = kT + ((size_t)h * NK + srow) * 32 + sg * 8;
        sstep  = KB * 32;
        ldsoff = srow * LDSROW + sg * 8;
    } else {
        sptr   = vb + (size_t)(h * DV + srow) * NK + sg * 8;
        sstep  = KB;
        ldsoff = KB * LDSROW + srow * LDSROW + sg * 8;
    }

    f32x4 o0 = {0.f, 0.f, 0.f, 0.f};
    f32x4 o1 = {0.f, 0.f, 0.f, 0.f};
    float rsum = 0.0f;
    const int shsrc = qcol + 16 * (2 * (g & 1));

    for (int c0 = 0; c0 < NK; c0 += KB) {
        uint4 sdat = *(const uint4*)sptr;
        sptr += sstep;
        __syncthreads();                       // previous chunk fully consumed
        *(uint4*)&lds[ldsoff] = sdat;
        __syncthreads();                       // chunk visible

        // S^T tiles: D[k,q] = sum_d K^T[k,d]*Q[d,q]
        short8v ka0 = *(const short8v*)&lds[(qcol)      * LDSROW + g * 8];
        short8v ka1 = *(const short8v*)&lds[(16 + qcol) * LDSROW + g * 8];
        f32x4 z = {0.f, 0.f, 0.f, 0.f};
        f32x4 s0 = __builtin_amdgcn_mfma_f32_16x16x32_bf16(ka0, qf.v, z, 0, 0, 0);
        f32x4 s1 = __builtin_amdgcn_mfma_f32_16x16x32_bf16(ka1, qf.v, z, 0, 0, 0);

        // P = exp(S/4); lane holds k = 4g+r (tile0), 16+4g+r (tile1) at col q
        float e0 = __expf(s0[0] * INV_SCALE), e1 = __expf(s0[1] * INV_SCALE);
        float e2 = __expf(s0[2] * INV_SCALE), e3 = __expf(s0[3] * INV_SCALE);
        float e4 = __expf(s1[0] * INV_SCALE), e5 = __expf(s1[1] * INV_SCALE);
        float e6 = __expf(s1[2] * INV_SCALE), e7 = __expf(s1[3] * INV_SCALE);
        rsum += ((e0 + e1) + (e2 + e3)) + ((e4 + e5) + (e6 + e7));

        uint w00 = pack2(e0, e1), w01 = pack2(e2, e3);   // tile0: k=4g+{0,1},{2,3}
        uint w10 = pack2(e4, e5), w11 = pack2(e6, e7);   // tile1: k=16+4g+{0,1},{2,3}

        // B2-frag: position (g,j) must hold P^T[k=8g+j][q]
        uint a0 = __shfl(w00, shsrc),      b0 = __shfl(w10, shsrc);
        uint a1 = __shfl(w01, shsrc),      b1 = __shfl(w11, shsrc);
        uint a2 = __shfl(w00, shsrc + 16), b2 = __shfl(w10, shsrc + 16);
        uint a3 = __shfl(w01, shsrc + 16), b3 = __shfl(w11, shsrc + 16);
        union { uint u[4]; short8v v; } bw;
        bw.u[0] = hi ? b0 : a0;
        bw.u[1] = hi ? b1 : a1;
        bw.u[2] = hi ? b2 : a2;
        bw.u[3] = hi ? b3 : a3;

        // PV: out^T[dv,q] += sum_k V[dv,k]*P^T[k,q]
        short8v va0 = *(const short8v*)&lds[KB * LDSROW + (qcol)      * LDSROW + g * 8];
        short8v va1 = *(const short8v*)&lds[KB * LDSROW + (16 + qcol) * LDSROW + g * 8];
        o0 = __builtin_amdgcn_mfma_f32_16x16x32_bf16(va0, bw.v, o0, 0, 0, 0);
        o1 = __builtin_amdgcn_mfma_f32_16x16x32_bf16(va1, bw.v, o1, 0, 0, 0);
    }

    // full row-sum for this q-col: lanes {l, l^16, l^32, l^48} hold disjoint k-partials
    rsum += __shfl_xor(rsum, 16);
    rsum += __shfl_xor(rsum, 32);
    float inv = 1.0f / rsum;

    #pragma unroll
    for (int r = 0; r < 4; ++r) {
        int dv0 = 4 * g + r;
        size_t i0 = (size_t)(h * DV + dv0) * NQ + q;
        out[i0] = o0[r] * inv + x[i0];
        size_t i1 = (size_t)(h * DV + 16 + dv0) * NQ + q;
        out[i1] = o1[r] * inv + x[i1];
    }
}

// ---------------- launcher ----------------
extern "C" void kernel_launch(void* const* d_in, const int* in_sizes, int n_in,
                              void* d_out, int out_size, void* d_ws, size_t ws_size,
                              hipStream_t stream) {
    const float* x   = (const float*)d_in[0];
    const float* w_q = (const float*)d_in[1];
    const float* b_q = (const float*)d_in[2];
    const float* w_k = (const float*)d_in[3];
    const float* b_k = (const float*)d_in[4];
    const float* w_v = (const float*)d_in[5];
    float* out = (float*)d_out;

    float*  xp = (float*)d_ws;                        // [256][2304] f32
    ushort* qb = (ushort*)(xp + (size_t)C_IN * NK);   // [128][9216] bf16
    ushort* kb = qb + (size_t)C_QK * NQ;              // [128][2304] bf16
    ushort* vb = kb + (size_t)C_QK * NK;              // [256][2304] bf16
    ushort* kT = vb + (size_t)C_IN * NK;              // [8][2304][32] bf16

    {
        int n = C_IN * NK;
        maxpool_kernel<<<(n + 255) / 256, 256, 0, stream>>>(x, xp);
    }
    {
        dim3 grid(NQ / BN, C_QK / BM);
        gemm_wx_bf16<<<grid, 256, 0, stream>>>(w_q, x, b_q, qb, C_QK, NQ);
    }
    {
        dim3 grid(NK / BN, C_QK / BM);
        gemm_wx_bf16<<<grid, 256, 0, stream>>>(w_k, xp, b_k, kb, C_QK, NK);
    }
    {
        dim3 grid(NK / BN, C_IN / BM);
        gemm_wx_bf16<<<grid, 256, 0, stream>>>(w_v, xp, nullptr, vb, C_IN, NK);
    }
    {
        int n = NH * NK;
        kpack_kernel<<<(n + 255) / 256, 256, 0, stream>>>(kb, kT);
    }
    {
        dim3 grid(NQ / 64, NH);
        attn_mfma<<<grid, 256, 0, stream>>>(qb, kT, vb, x, out);
    }
}

// Round 3
// 180.559 us; speedup vs baseline: 5.6891x; 1.0811x over previous
//
#include <hip/hip_runtime.h>
#include <hip/hip_bf16.h>
#include <math.h>

// Problem constants
#define C_IN   256
#define C_QK   128
#define NH     8
#define H_     96
#define W_     96
#define NQ     (H_*W_)          // 9216
#define HD     (H_/2)           // 48
#define WD     (W_/2)           // 48
#define NK     (HD*WD)          // 2304
#define DQ     16               // C_QK/NH
#define DV     32               // C_IN/NH
#define Q_SCALE 0.25f           // folded into q-GEMM epilogue

typedef __attribute__((ext_vector_type(8)))  short short8v;
typedef __attribute__((ext_vector_type(4)))  float f32x4;
typedef __attribute__((ext_vector_type(16))) float f32x16;
typedef int v2i __attribute__((ext_vector_type(2)));

static __device__ inline ushort bf16r(float f) {
    __hip_bfloat16 h = __float2bfloat16(f);
    return *reinterpret_cast<ushort*>(&h);
}
static __device__ inline uint pack2(float lo, float hi) {
    return (uint)bf16r(lo) | ((uint)bf16r(hi) << 16);
}

// half-swap: x = [a.lo | b.lo], y = [a.hi | b.hi]  (32-lane halves)
static __device__ inline void lswap(uint a, uint b, uint& x, uint& y, int hi) {
#if __has_builtin(__builtin_amdgcn_permlane32_swap)
    v2i r = __builtin_amdgcn_permlane32_swap((int)a, (int)b, false, false);
    x = (uint)r.x;
    y = (uint)r.y;
#else
    uint bx = (uint)__shfl_xor((int)b, 32);
    uint ax = (uint)__shfl_xor((int)a, 32);
    x = hi ? bx : a;
    y = hi ? b : ax;
#endif
}

// ---------------- maxpool 2x2 ----------------
__global__ __launch_bounds__(256) void maxpool_kernel(const float* __restrict__ x,
                                                      float* __restrict__ xp) {
    int idx = blockIdx.x * 256 + threadIdx.x;
    if (idx >= C_IN * NK) return;
    int c = idx / NK;
    int r = idx - c * NK;
    int y = r / WD, xx = r - y * WD;
    const float* p = &x[c * NQ + (2 * y) * W_ + 2 * xx];
    float m = fmaxf(fmaxf(p[0], p[1]), fmaxf(p[W_], p[W_ + 1]));
    xp[idx] = m;
}

// -------- conv1x1 GEMM (fp32 compute, bf16 out): C = (W*X + b) * scale --------
#define BM 64
#define BN 64
#define BK 16
#define AS_LD 68

__global__ __launch_bounds__(256) void gemm_wx_bf16(const float* __restrict__ Wm,
                                                    const float* __restrict__ X,
                                                    const float* __restrict__ bias,
                                                    ushort* __restrict__ C,
                                                    int M, int N, float scale) {
    const int K = C_IN;
    __shared__ float As[BK * AS_LD];  // As[k][m]
    __shared__ float Bs[BK * BN];     // Bs[k][n]

    int tid = threadIdx.x;
    int tn = tid & 15;
    int tm = tid >> 4;
    int m0 = tm * 4, n0 = tn * 4;
    int mBlk = blockIdx.y * BM;
    int nBlk = blockIdx.x * BN;

    float acc[4][4] = {};

    for (int k0 = 0; k0 < K; k0 += BK) {
        {
            int lm = tid >> 2;
            int lk = (tid & 3) * 4;
            float4 w4 = *(const float4*)&Wm[(mBlk + lm) * K + k0 + lk];
            As[(lk + 0) * AS_LD + lm] = w4.x;
            As[(lk + 1) * AS_LD + lm] = w4.y;
            As[(lk + 2) * AS_LD + lm] = w4.z;
            As[(lk + 3) * AS_LD + lm] = w4.w;
        }
        {
            int lk = tid >> 6;
            int ln = tid & 63;
            #pragma unroll
            for (int r = 0; r < 4; ++r)
                Bs[(lk * 4 + r) * BN + ln] = X[(size_t)(k0 + lk * 4 + r) * N + nBlk + ln];
        }
        __syncthreads();
        #pragma unroll
        for (int kk = 0; kk < BK; ++kk) {
            float4 a4 = *(const float4*)&As[kk * AS_LD + m0];
            float4 b4 = *(const float4*)&Bs[kk * BN + n0];
            float a[4] = {a4.x, a4.y, a4.z, a4.w};
            float b[4] = {b4.x, b4.y, b4.z, b4.w};
            #pragma unroll
            for (int i = 0; i < 4; ++i)
                #pragma unroll
                for (int j = 0; j < 4; ++j)
                    acc[i][j] += a[i] * b[j];
        }
        __syncthreads();
    }

    #pragma unroll
    for (int i = 0; i < 4; ++i) {
        int m = mBlk + m0 + i;
        float bv = bias ? bias[m] : 0.0f;
        ushort4 o;
        o.x = bf16r((acc[i][0] + bv) * scale);
        o.y = bf16r((acc[i][1] + bv) * scale);
        o.z = bf16r((acc[i][2] + bv) * scale);
        o.w = bf16r((acc[i][3] + bv) * scale);
        *(ushort4*)&C[(size_t)m * N + nBlk + n0] = o;
    }
}

// -------- pack K [128][2304] bf16 -> K^T [8][2304][16] bf16 --------
__global__ __launch_bounds__(256) void kpack_kernel(const ushort* __restrict__ kb,
                                                    ushort* __restrict__ kT) {
    int idx = blockIdx.x * 256 + threadIdx.x;   // over 8*2304
    if (idx >= NH * NK) return;
    int h = idx / NK, kk = idx - h * NK;
    union { ushort s[16]; uint4 v[2]; } t;
    #pragma unroll
    for (int d = 0; d < 16; ++d) t.s[d] = kb[(size_t)(h * DQ + d) * NK + kk];
    uint4* dst = (uint4*)&kT[(size_t)idx * 16];
    dst[0] = t.v[0];
    dst[1] = t.v[1];
}

// ---------------- fused attention: 32x32x16 MFMA, no LDS, no barriers ----------------
// One wave handles 32 queries for one head. K/V fragments read straight from
// global (L1/L2-resident: 294 KB per head), depth-1 register prefetch.
#define KB 32

__global__ __launch_bounds__(256) void attn_mfma32(const ushort* __restrict__ qb,
                                                   const ushort* __restrict__ kT,
                                                   const ushort* __restrict__ vb,
                                                   const float* __restrict__ x,
                                                   float* __restrict__ out) {
    const int h    = blockIdx.y;
    const int tid  = threadIdx.x;
    const int wv   = tid >> 6;
    const int lane = tid & 63;
    const int q31  = lane & 31;
    const int hi   = lane >> 5;
    const int q    = blockIdx.x * 128 + wv * 32 + q31;

    union U8 { ushort u[8]; short8v v; };
    union B8 { uint u[4]; short8v v; };

    // Q B-frag: lane holds Q[d = 8*hi + j][q]  (q pre-scaled by 1/4 in GEMM)
    U8 qf;
    {
        const ushort* qp = qb + (size_t)(h * DQ + 8 * hi) * NQ + q;
        #pragma unroll
        for (int j = 0; j < 8; ++j) { qf.u[j] = *qp; qp += NQ; }
    }

    // per-lane base pointers
    const ushort* kbase = kT + ((size_t)h * NK + q31) * 16 + 8 * hi;   // A: K^T[k=c0+q31][d=8hi+j]
    const ushort* vbase = vb + (size_t)(h * DV + q31) * NK + 8 * hi;   // A: V[dv=q31][k=c0+8hi+j]

    // prefetch chunk 0
    short8v kd = *(const short8v*)kbase;
    short8v v0 = *(const short8v*)vbase;
    short8v v1 = *(const short8v*)(vbase + 16);

    f32x16 o;
    #pragma unroll
    for (int r = 0; r < 16; ++r) o[r] = 0.0f;
    f32x16 zc;
    #pragma unroll
    for (int r = 0; r < 16; ++r) zc[r] = 0.0f;
    float rsum = 0.0f;

    for (int c0 = 0; c0 < NK; c0 += KB) {
        short8v kc = kd, v0c = v0, v1c = v1;
        int cn = c0 + KB;
        if (cn >= NK) cn = 0;                       // wrap: keeps loads in-bounds, no branch
        kd = *(const short8v*)(kbase + (size_t)cn * 16);
        v0 = *(const short8v*)(vbase + cn);
        v1 = *(const short8v*)(vbase + cn + 16);

        // S^T[k 32][q 32] = K^T(32x16) * Q(16x32); lane holds col q, rows crow(r,hi)
        f32x16 s = __builtin_amdgcn_mfma_f32_32x32x16_bf16(kc, qf.v, zc, 0, 0, 0);

        // P = exp(S); reg r -> k = (r&3) + 8*(r>>2) + 4*hi
        float e[16];
        #pragma unroll
        for (int r = 0; r < 16; ++r) e[r] = __expf(s[r]);
        #pragma unroll
        for (int r = 0; r < 16; ++r) rsum += e[r];

        // pack pairs and half-swap into PV B-frags (k = 8*hi + j per MFMA)
        uint a0 = pack2(e[0],  e[1]),  b0 = pack2(e[4],  e[5]);
        uint a1 = pack2(e[2],  e[3]),  b1 = pack2(e[6],  e[7]);
        uint a2 = pack2(e[8],  e[9]),  b2 = pack2(e[12], e[13]);
        uint a3 = pack2(e[10], e[11]), b3 = pack2(e[14], e[15]);

        B8 B1, B2;
        lswap(a0, b0, B1.u[0], B1.u[2], hi);
        lswap(a1, b1, B1.u[1], B1.u[3], hi);
        lswap(a2, b2, B2.u[0], B2.u[2], hi);
        lswap(a3, b3, B2.u[1], B2.u[3], hi);

        // out^T[dv 32][q 32] += V(32x16k) * P^T(16k x 32q), two k-halves
        o = __builtin_amdgcn_mfma_f32_32x32x16_bf16(v0c, B1.v, o, 0, 0, 0);
        o = __builtin_amdgcn_mfma_f32_32x32x16_bf16(v1c, B2.v, o, 0, 0, 0);
    }

    // lanes l and l^32 hold disjoint k-halves of the denominator for col q
    rsum += __shfl_xor(rsum, 32);
    float inv = 1.0f / rsum;

    #pragma unroll
    for (int r = 0; r < 16; ++r) {
        int dv = (r & 3) + 8 * (r >> 2) + 4 * hi;
        size_t i0 = (size_t)(h * DV + dv) * NQ + q;
        out[i0] = o[r] * inv + x[i0];
    }
}

// ---------------- launcher ----------------
extern "C" void kernel_launch(void* const* d_in, const int* in_sizes, int n_in,
                              void* d_out, int out_size, void* d_ws, size_t ws_size,
                              hipStream_t stream) {
    const float* x   = (const float*)d_in[0];
    const float* w_q = (const float*)d_in[1];
    const float* b_q = (const float*)d_in[2];
    const float* w_k = (const float*)d_in[3];
    const float* b_k = (const float*)d_in[4];
    const float* w_v = (const float*)d_in[5];
    float* out = (float*)d_out;

    float*  xp = (float*)d_ws;                        // [256][2304] f32
    ushort* qb = (ushort*)(xp + (size_t)C_IN * NK);   // [128][9216] bf16 (pre-scaled 1/4)
    ushort* kb = qb + (size_t)C_QK * NQ;              // [128][2304] bf16
    ushort* vb = kb + (size_t)C_QK * NK;              // [256][2304] bf16
    ushort* kT = vb + (size_t)C_IN * NK;              // [8][2304][16] bf16

    {
        int n = C_IN * NK;
        maxpool_kernel<<<(n + 255) / 256, 256, 0, stream>>>(x, xp);
    }
    {
        dim3 grid(NQ / BN, C_QK / BM);
        gemm_wx_bf16<<<grid, 256, 0, stream>>>(w_q, x, b_q, qb, C_QK, NQ, Q_SCALE);
    }
    {
        dim3 grid(NK / BN, C_QK / BM);
        gemm_wx_bf16<<<grid, 256, 0, stream>>>(w_k, xp, b_k, kb, C_QK, NK, 1.0f);
    }
    {
        dim3 grid(NK / BN, C_IN / BM);
        gemm_wx_bf16<<<grid, 256, 0, stream>>>(w_v, xp, nullptr, vb, C_IN, NK, 1.0f);
    }
    {
        int n = NH * NK;
        kpack_kernel<<<(n + 255) / 256, 256, 0, stream>>>(kb, kT);
    }
    {
        dim3 grid(NQ / 128, NH);
        attn_mfma32<<<grid, 256, 0, stream>>>(qb, kT, vb, x, out);
    }
}

// Round 4
// 117.975 us; speedup vs baseline: 8.7071x; 1.5305x over previous
//
#include <hip/hip_runtime.h>
#include <hip/hip_bf16.h>
#include <math.h>

// Problem constants
#define C_IN   256
#define C_QK   128
#define NH     8
#define H_     96
#define W_     96
#define NQ     (H_*W_)          // 9216
#define HD     48
#define WD     48
#define NK     (HD*WD)          // 2304
#define DQ     16
#define DV     32
#define NQC    (NQ/32)          // 288 query chunks
#define NKC    (NK/32)          // 72 key chunks
#define KSTEPS (C_IN/16)        // 16 MFMA k-steps per GEMM
#define QS     0.3606737602222409f   // 0.25 * log2(e): folds sim-scale + exp->exp2

typedef __attribute__((ext_vector_type(8)))  short short8v;
typedef __attribute__((ext_vector_type(16))) float f32x16;
typedef __attribute__((ext_vector_type(2)))  int   v2i;

union B8u { uint u[4]; short8v v; };

static __device__ inline ushort bf16r(float f) {
    __hip_bfloat16 h = __float2bfloat16(f);
    return *reinterpret_cast<ushort*>(&h);
}
// packed f32x2 -> bf16x2 (RNE), single instruction
static __device__ inline uint cvtpk(float lo, float hi) {
    uint r;
    asm("v_cvt_pk_bf16_f32 %0, %1, %2" : "=v"(r) : "v"(lo), "v"(hi));
    return r;
}
// half-swap: x = [a@hi0 | b@hi0], y = [a@hi1 | b@hi1] viewed per-lane
static __device__ inline void lswap(uint a, uint b, uint& x, uint& y, int hi) {
#if __has_builtin(__builtin_amdgcn_permlane32_swap)
    v2i r = __builtin_amdgcn_permlane32_swap((int)a, (int)b, false, false);
    x = (uint)r.x;
    y = (uint)r.y;
#else
    uint bx = (uint)__shfl_xor((int)b, 32);
    uint ax = (uint)__shfl_xor((int)a, 32);
    x = hi ? bx : a;
    y = hi ? b : ax;
#endif
}
static __device__ inline float fexp2(float v) {
#if __has_builtin(__builtin_amdgcn_exp2f)
    return __builtin_amdgcn_exp2f(v);
#else
    return __expf(v * 0.6931471805599453f);
#endif
}

// ---------------- prep: pack x, pooled-x, weights into MFMA fragment streams ----------------
// Fragment unit = (chunk, kstep, lane) -> 8 bf16 (16B). Layout [..][ks][64][8].
#define U_XB   (NQC*KSTEPS*64)     // 294912
#define U_XPB  (NKC*KSTEPS*64)     // 73728
#define U_WQ   (4*KSTEPS*64)       // 4096   (128 rows / 32)
#define U_WK   (4*KSTEPS*64)       // 4096
#define U_WV   (8*KSTEPS*64)       // 8192   (256 rows / 32)
#define U_FRAG (U_XB+U_XPB+U_WQ+U_WK+U_WV)  // 385024
#define U_TOT  (U_FRAG + 128)

__global__ __launch_bounds__(256) void prep_kernel(
    const float* __restrict__ x,  const float* __restrict__ wq, const float* __restrict__ bq,
    const float* __restrict__ wk, const float* __restrict__ wv,
    ushort* __restrict__ xbP, ushort* __restrict__ xpbP,
    ushort* __restrict__ wqP, ushort* __restrict__ wkP, ushort* __restrict__ wvP,
    float* __restrict__ bqs)
{
    int t = blockIdx.x * 256 + threadIdx.x;
    if (t >= U_TOT) return;
    if (t >= U_FRAG) { int i = t - U_FRAG; bqs[i] = bq[i] * QS; return; }

    union { ushort s[8]; uint4 v; } ou;
    int u = t;
    if (u < U_XB) {                              // x -> B-frag stream [288][16][64][8]
        int l = u & 63, rest = u >> 6;
        int ks = rest & 15, nc = rest >> 4;
        int n  = nc * 32 + (l & 31);
        int k0 = ks * 16 + 8 * (l >> 5);
        #pragma unroll
        for (int j = 0; j < 8; ++j) ou.s[j] = bf16r(x[(size_t)(k0 + j) * NQ + n]);
        *(uint4*)&xbP[(size_t)u * 8] = ou.v;
        return;
    }
    u -= U_XB;
    if (u < U_XPB) {                             // maxpool(x) -> frag stream [72][16][64][8]
        int l = u & 63, rest = u >> 6;
        int ks = rest & 15, nc = rest >> 4;
        int np = nc * 32 + (l & 31);
        int k0 = ks * 16 + 8 * (l >> 5);
        int py = np / WD, px = np - py * WD;
        const float* base = x + (2 * py) * W_ + 2 * px;
        #pragma unroll
        for (int j = 0; j < 8; ++j) {
            const float* p = base + (size_t)(k0 + j) * NQ;
            ou.s[j] = bf16r(fmaxf(fmaxf(p[0], p[1]), fmaxf(p[W_], p[W_ + 1])));
        }
        *(uint4*)&xpbP[(size_t)u * 8] = ou.v;
        return;
    }
    u -= U_XPB;
    if (u < U_WQ) {                              // w_q * QS -> frag [4][16][64][8]
        int l = u & 63, ks = (u >> 6) & 15, mb = u >> 10;
        int m = mb * 32 + (l & 31), k0 = ks * 16 + 8 * (l >> 5);
        #pragma unroll
        for (int j = 0; j < 8; ++j) ou.s[j] = bf16r(wq[m * C_IN + k0 + j] * QS);
        *(uint4*)&wqP[(size_t)u * 8] = ou.v;
        return;
    }
    u -= U_WQ;
    if (u < U_WK) {                              // w_k -> frag [4][16][64][8]
        int l = u & 63, ks = (u >> 6) & 15, mb = u >> 10;
        int m = mb * 32 + (l & 31), k0 = ks * 16 + 8 * (l >> 5);
        #pragma unroll
        for (int j = 0; j < 8; ++j) ou.s[j] = bf16r(wk[m * C_IN + k0 + j]);
        *(uint4*)&wkP[(size_t)u * 8] = ou.v;
        return;
    }
    u -= U_WK;
    {                                            // w_v -> frag [8][16][64][8]
        int l = u & 63, ks = (u >> 6) & 15, cb = u >> 10;
        int c = cb * 32 + (l & 31), k0 = ks * 16 + 8 * (l >> 5);
        #pragma unroll
        for (int j = 0; j < 8; ++j) ou.s[j] = bf16r(wv[c * C_IN + k0 + j]);
        *(uint4*)&wvP[(size_t)u * 8] = ou.v;
    }
}

// ---------------- shared GEMM pieces ----------------
static __device__ inline f32x16 mfma_loop(const ushort* __restrict__ A,
                                          const ushort* __restrict__ B) {
    f32x16 acc;
    #pragma unroll
    for (int r = 0; r < 16; ++r) acc[r] = 0.0f;
    #pragma unroll
    for (int s = 0; s < KSTEPS; ++s) {
        short8v a = *(const short8v*)(A + (size_t)s * 512);
        short8v b = *(const short8v*)(B + (size_t)s * 512);
        acc = __builtin_amdgcn_mfma_f32_32x32x16_bf16(a, b, acc, 0, 0, 0);
    }
    return acc;
}
// C-frag (rows on regs, cols on lanes) -> two operand frags: F1 rows 0..15, F2 rows 16..31
static __device__ inline void xform(const f32x16& acc, int hi, short8v& F1, short8v& F2) {
    uint a0 = cvtpk(acc[0],  acc[1]),  a1 = cvtpk(acc[2],  acc[3]);
    uint b0 = cvtpk(acc[4],  acc[5]),  b1 = cvtpk(acc[6],  acc[7]);
    uint a2 = cvtpk(acc[8],  acc[9]),  a3 = cvtpk(acc[10], acc[11]);
    uint b2 = cvtpk(acc[12], acc[13]), b3 = cvtpk(acc[14], acc[15]);
    B8u f1, f2;
    lswap(a0, b0, f1.u[0], f1.u[2], hi);
    lswap(a1, b1, f1.u[1], f1.u[3], hi);
    lswap(a2, b2, f2.u[0], f2.u[2], hi);
    lswap(a3, b3, f2.u[1], f2.u[3], hi);
    F1 = f1.v; F2 = f2.v;
}

// q/k GEMM: C[m=d][n] = W[m,:]*X[:,n] + bias; writes per-head operand frags
__global__ __launch_bounds__(256) void gemm_qk(const ushort* __restrict__ Wp,
                                               const ushort* __restrict__ Xp,
                                               const float* __restrict__ bias,
                                               ushort* __restrict__ outP, int NC) {
    int lane = threadIdx.x & 63, wvi = threadIdx.x >> 6;
    int hi = lane >> 5;
    int mb = blockIdx.x;                    // 32-row block (2 heads)
    int nc = blockIdx.y * 4 + wvi;          // 32-col chunk
    const ushort* A = Wp + ((size_t)(mb * KSTEPS) * 64 + lane) * 8;
    const ushort* B = Xp + ((size_t)(nc * KSTEPS) * 64 + lane) * 8;
    f32x16 acc = mfma_loop(A, B);
    #pragma unroll
    for (int r = 0; r < 16; ++r)
        acc[r] += bias[mb * 32 + (r & 3) + 8 * (r >> 2) + 4 * hi];
    short8v F1, F2;
    xform(acc, hi, F1, F2);
    *(short8v*)&outP[((size_t)((2 * mb)     * NC + nc) * 64 + lane) * 8] = F1;
    *(short8v*)&outP[((size_t)((2 * mb + 1) * NC + nc) * 64 + lane) * 8] = F2;
}

// v GEMM computed transposed: C^T[key][c] -> vpack[h][kc][t][64][8]
__global__ __launch_bounds__(256) void gemm_v(const ushort* __restrict__ Xp,
                                              const ushort* __restrict__ Wvp,
                                              ushort* __restrict__ vpack) {
    int lane = threadIdx.x & 63, wvi = threadIdx.x >> 6;
    int hi = lane >> 5;
    int cb = blockIdx.x;                    // head (32 channels)
    int kc = blockIdx.y * 4 + wvi;          // key chunk
    const ushort* A = Xp  + ((size_t)(kc * KSTEPS) * 64 + lane) * 8;  // X^T rows=keys
    const ushort* B = Wvp + ((size_t)(cb * KSTEPS) * 64 + lane) * 8;  // W^T cols=c
    f32x16 acc = mfma_loop(A, B);
    short8v F1, F2;
    xform(acc, hi, F1, F2);
    *(short8v*)&vpack[((size_t)((cb * NKC + kc) * 2 + 0) * 64 + lane) * 8] = F1;
    *(short8v*)&vpack[((size_t)((cb * NKC + kc) * 2 + 1) * 64 + lane) * 8] = F2;
}

// ---------------- fused attention: key-split x2 waves, packed b128 streams ----------------
__global__ __launch_bounds__(256) void attn_kernel(const ushort* __restrict__ qpack,
                                                   const ushort* __restrict__ kpack,
                                                   const ushort* __restrict__ vpack,
                                                   const float* __restrict__ x,
                                                   float* __restrict__ out) {
    __shared__ float comb[2 * 64 * 17];
    const int h = blockIdx.y;
    const int tid = threadIdx.x, lane = tid & 63;
    const int wvi = tid >> 6;
    const int qg = wvi & 1, kh = wvi >> 1;      // q-group, key-half
    const int q31 = lane & 31, hi = lane >> 5;
    const int qc = blockIdx.x * 2 + qg;
    const int q = qc * 32 + q31;

    short8v qf = *(const short8v*)&qpack[((size_t)(h * NQC + qc) * 64 + lane) * 8];

    const ushort* kp = kpack + ((size_t)(h * NKC + kh * 36) * 64 + lane) * 8;
    const ushort* vp = vpack + ((size_t)(h * NKC + kh * 36) * 2 * 64 + lane) * 8;

    short8v kf = *(const short8v*)kp;
    short8v v0 = *(const short8v*)vp;
    short8v v1 = *(const short8v*)(vp + 512);

    f32x16 o, zc;
    #pragma unroll
    for (int r = 0; r < 16; ++r) { o[r] = 0.0f; zc[r] = 0.0f; }
    float rsum = 0.0f;

    #pragma unroll 2
    for (int c = 0; c < 36; ++c) {
        short8v kcur = kf, v0c = v0, v1c = v1;
        int cn = (c == 35) ? 0 : (c + 1);       // wrap keeps loads in-bounds; data unused
        kf = *(const short8v*)(kp + (size_t)cn * 512);
        v0 = *(const short8v*)(vp + (size_t)cn * 1024);
        v1 = *(const short8v*)(vp + (size_t)cn * 1024 + 512);

        // S^T[key][q] (pre-scaled so exp2 is exact softmax kernel)
        f32x16 s = __builtin_amdgcn_mfma_f32_32x32x16_bf16(kcur, qf, zc, 0, 0, 0);

        float e[16];
        #pragma unroll
        for (int r = 0; r < 16; ++r) e[r] = fexp2(s[r]);
        float t0 = 0.0f;
        #pragma unroll
        for (int r = 0; r < 16; ++r) t0 += e[r];
        rsum += t0;

        uint a0 = cvtpk(e[0],  e[1]),  a1 = cvtpk(e[2],  e[3]);
        uint b0 = cvtpk(e[4],  e[5]),  b1 = cvtpk(e[6],  e[7]);
        uint a2 = cvtpk(e[8],  e[9]),  a3 = cvtpk(e[10], e[11]);
        uint b2 = cvtpk(e[12], e[13]), b3 = cvtpk(e[14], e[15]);
        B8u B1, B2;
        lswap(a0, b0, B1.u[0], B1.u[2], hi);
        lswap(a1, b1, B1.u[1], B1.u[3], hi);
        lswap(a2, b2, B2.u[0], B2.u[2], hi);
        lswap(a3, b3, B2.u[1], B2.u[3], hi);

        o = __builtin_amdgcn_mfma_f32_32x32x16_bf16(v0c, B1.v, o, 0, 0, 0);
        o = __builtin_amdgcn_mfma_f32_32x32x16_bf16(v1c, B2.v, o, 0, 0, 0);
    }

    rsum += __shfl_xor(rsum, 32);

    if (kh == 1) {
        float* cb_ = &comb[(qg * 64 + lane) * 17];
        #pragma unroll
        for (int r = 0; r < 16; ++r) cb_[r] = o[r];
        cb_[16] = rsum;
    }
    __syncthreads();
    if (kh == 0) {
        const float* cb_ = &comb[(qg * 64 + lane) * 17];
        #pragma unroll
        for (int r = 0; r < 16; ++r) o[r] += cb_[r];
        float inv = 1.0f / (rsum + cb_[16]);
        #pragma unroll
        for (int r = 0; r < 16; ++r) {
            int dv = (r & 3) + 8 * (r >> 2) + 4 * hi;
            size_t i0 = (size_t)(h * DV + dv) * NQ + q;
            out[i0] = o[r] * inv + x[i0];
        }
    }
}

// ---------------- launcher ----------------
extern "C" void kernel_launch(void* const* d_in, const int* in_sizes, int n_in,
                              void* d_out, int out_size, void* d_ws, size_t ws_size,
                              hipStream_t stream) {
    const float* x  = (const float*)d_in[0];
    const float* wq = (const float*)d_in[1];
    const float* bq = (const float*)d_in[2];
    const float* wk = (const float*)d_in[3];
    const float* bk = (const float*)d_in[4];
    const float* wv = (const float*)d_in[5];
    float* out = (float*)d_out;

    ushort* p = (ushort*)d_ws;
    ushort* xbP   = p;  p += (size_t)U_XB  * 8;          // 2,359,296
    ushort* xpbP  = p;  p += (size_t)U_XPB * 8;          //   589,824
    ushort* wqP   = p;  p += (size_t)U_WQ  * 8;          //    32,768
    ushort* wkP   = p;  p += (size_t)U_WK  * 8;          //    32,768
    ushort* wvP   = p;  p += (size_t)U_WV  * 8;          //    65,536
    ushort* qpack = p;  p += (size_t)NH * NQC * 64 * 8;  // 1,179,648
    ushort* kpack = p;  p += (size_t)NH * NKC * 64 * 8;  //   294,912
    ushort* vpack = p;  p += (size_t)NH * NKC * 2 * 64 * 8; // 589,824
    float*  bqs   = (float*)p;                           // 128 f32

    prep_kernel<<<(U_TOT + 255) / 256, 256, 0, stream>>>(x, wq, bq, wk, wv,
                                                         xbP, xpbP, wqP, wkP, wvP, bqs);
    gemm_qk<<<dim3(4, NQC / 4), 256, 0, stream>>>(wqP, xbP, bqs, qpack, NQC);
    gemm_qk<<<dim3(4, NKC / 4), 256, 0, stream>>>(wkP, xpbP, bk, kpack, NKC);
    gemm_v <<<dim3(NH, NKC / 4), 256, 0, stream>>>(xpbP, wvP, vpack);
    attn_kernel<<<dim3(NQC / 2, NH), 256, 0, stream>>>(qpack, kpack, vpack, x, out);
}

// Round 5
// 105.818 us; speedup vs baseline: 9.7074x; 1.1149x over previous
//
#include <hip/hip_runtime.h>
#include <hip/hip_bf16.h>
#include <math.h>

// Problem constants
#define C_IN   256
#define C_QK   128
#define NH     8
#define H_     96
#define W_     96
#define NQ     (H_*W_)          // 9216
#define HD     48
#define WD     48
#define NK     (HD*WD)          // 2304
#define DQ     16
#define DV     32
#define NQC    (NQ/32)          // 288 query chunks
#define NKC    (NK/32)          // 72 key chunks
#define QPAIRS (NQC/2)          // 144
#define KQRT   (NKC/4)          // 18 key chunks per wave (4-way key split)
#define KSTEPS (C_IN/16)        // 16 MFMA k-steps per GEMM
#define QS     0.3606737602222409f   // 0.25 * log2(e): folds sim-scale + exp->exp2

typedef __attribute__((ext_vector_type(8)))  short short8v;
typedef __attribute__((ext_vector_type(16))) float f32x16;
typedef __attribute__((ext_vector_type(2)))  int   v2i;

union B8u { uint u[4]; short8v v; };

static __device__ inline ushort bf16r(float f) {
    __hip_bfloat16 h = __float2bfloat16(f);
    return *reinterpret_cast<ushort*>(&h);
}
static __device__ inline uint cvtpk(float lo, float hi) {
    uint r;
    asm("v_cvt_pk_bf16_f32 %0, %1, %2" : "=v"(r) : "v"(lo), "v"(hi));
    return r;
}
static __device__ inline void lswap(uint a, uint b, uint& x, uint& y, int hi) {
#if __has_builtin(__builtin_amdgcn_permlane32_swap)
    v2i r = __builtin_amdgcn_permlane32_swap((int)a, (int)b, false, false);
    x = (uint)r.x;
    y = (uint)r.y;
#else
    uint bx = (uint)__shfl_xor((int)b, 32);
    uint ax = (uint)__shfl_xor((int)a, 32);
    x = hi ? bx : a;
    y = hi ? b : ax;
#endif
}
static __device__ inline float fexp2(float v) {
#if __has_builtin(__builtin_amdgcn_exp2f)
    return __builtin_amdgcn_exp2f(v);
#else
    return __expf(v * 0.6931471805599453f);
#endif
}

// ---------------- prep: pack x, pooled-x, weights into MFMA fragment streams ----------------
#define U_XB   (NQC*KSTEPS*64)     // 294912
#define U_XPB  (NKC*KSTEPS*64)     // 73728
#define U_WQ   (4*KSTEPS*64)       // 4096
#define U_WK   (4*KSTEPS*64)       // 4096
#define U_WV   (8*KSTEPS*64)       // 8192
#define U_FRAG (U_XB+U_XPB+U_WQ+U_WK+U_WV)
#define U_TOT  (U_FRAG + 128)

__global__ __launch_bounds__(256) void prep_kernel(
    const float* __restrict__ x,  const float* __restrict__ wq, const float* __restrict__ bq,
    const float* __restrict__ wk, const float* __restrict__ wv,
    ushort* __restrict__ xbP, ushort* __restrict__ xpbP,
    ushort* __restrict__ wqP, ushort* __restrict__ wkP, ushort* __restrict__ wvP,
    float* __restrict__ bqs)
{
    int t = blockIdx.x * 256 + threadIdx.x;
    if (t >= U_TOT) return;
    if (t >= U_FRAG) { int i = t - U_FRAG; bqs[i] = bq[i] * QS; return; }

    union { ushort s[8]; uint4 v; } ou;
    int u = t;
    if (u < U_XB) {
        int l = u & 63, rest = u >> 6;
        int ks = rest & 15, nc = rest >> 4;
        int n  = nc * 32 + (l & 31);
        int k0 = ks * 16 + 8 * (l >> 5);
        #pragma unroll
        for (int j = 0; j < 8; ++j) ou.s[j] = bf16r(x[(size_t)(k0 + j) * NQ + n]);
        *(uint4*)&xbP[(size_t)u * 8] = ou.v;
        return;
    }
    u -= U_XB;
    if (u < U_XPB) {
        int l = u & 63, rest = u >> 6;
        int ks = rest & 15, nc = rest >> 4;
        int np = nc * 32 + (l & 31);
        int k0 = ks * 16 + 8 * (l >> 5);
        int py = np / WD, px = np - py * WD;
        const float* base = x + (2 * py) * W_ + 2 * px;
        #pragma unroll
        for (int j = 0; j < 8; ++j) {
            const float* p = base + (size_t)(k0 + j) * NQ;
            ou.s[j] = bf16r(fmaxf(fmaxf(p[0], p[1]), fmaxf(p[W_], p[W_ + 1])));
        }
        *(uint4*)&xpbP[(size_t)u * 8] = ou.v;
        return;
    }
    u -= U_XPB;
    if (u < U_WQ) {
        int l = u & 63, ks = (u >> 6) & 15, mb = u >> 10;
        int m = mb * 32 + (l & 31), k0 = ks * 16 + 8 * (l >> 5);
        #pragma unroll
        for (int j = 0; j < 8; ++j) ou.s[j] = bf16r(wq[m * C_IN + k0 + j] * QS);
        *(uint4*)&wqP[(size_t)u * 8] = ou.v;
        return;
    }
    u -= U_WQ;
    if (u < U_WK) {
        int l = u & 63, ks = (u >> 6) & 15, mb = u >> 10;
        int m = mb * 32 + (l & 31), k0 = ks * 16 + 8 * (l >> 5);
        #pragma unroll
        for (int j = 0; j < 8; ++j) ou.s[j] = bf16r(wk[m * C_IN + k0 + j]);
        *(uint4*)&wkP[(size_t)u * 8] = ou.v;
        return;
    }
    u -= U_WK;
    {
        int l = u & 63, ks = (u >> 6) & 15, cb = u >> 10;
        int c = cb * 32 + (l & 31), k0 = ks * 16 + 8 * (l >> 5);
        #pragma unroll
        for (int j = 0; j < 8; ++j) ou.s[j] = bf16r(wv[c * C_IN + k0 + j]);
        *(uint4*)&wvP[(size_t)u * 8] = ou.v;
    }
}

// ---------------- shared GEMM pieces ----------------
static __device__ inline f32x16 mfma_loop(const ushort* __restrict__ A,
                                          const ushort* __restrict__ B) {
    f32x16 acc;
    #pragma unroll
    for (int r = 0; r < 16; ++r) acc[r] = 0.0f;
    #pragma unroll
    for (int s = 0; s < KSTEPS; ++s) {
        short8v a = *(const short8v*)(A + (size_t)s * 512);
        short8v b = *(const short8v*)(B + (size_t)s * 512);
        acc = __builtin_amdgcn_mfma_f32_32x32x16_bf16(a, b, acc, 0, 0, 0);
    }
    return acc;
}
static __device__ inline void xform(const f32x16& acc, int hi, short8v& F1, short8v& F2) {
    uint a0 = cvtpk(acc[0],  acc[1]),  a1 = cvtpk(acc[2],  acc[3]);
    uint b0 = cvtpk(acc[4],  acc[5]),  b1 = cvtpk(acc[6],  acc[7]);
    uint a2 = cvtpk(acc[8],  acc[9]),  a3 = cvtpk(acc[10], acc[11]);
    uint b2 = cvtpk(acc[12], acc[13]), b3 = cvtpk(acc[14], acc[15]);
    B8u f1, f2;
    lswap(a0, b0, f1.u[0], f1.u[2], hi);
    lswap(a1, b1, f1.u[1], f1.u[3], hi);
    lswap(a2, b2, f2.u[0], f2.u[2], hi);
    lswap(a3, b3, f2.u[1], f2.u[3], hi);
    F1 = f1.v; F2 = f2.v;
}

// -------- fused q/k/v GEMM: one 32x32 tile per wave, 2016 tiles flat --------
#define T_Q 1152            // 4 mb * 288 nc
#define T_K (T_Q + 288)     // + 4 mb * 72 nc
#define T_ALL (T_K + 576)   // + 8 cb * 72 kc

__global__ __launch_bounds__(256) void gemm_fused(
    const ushort* __restrict__ xbP, const ushort* __restrict__ xpbP,
    const ushort* __restrict__ wqP, const ushort* __restrict__ wkP,
    const ushort* __restrict__ wvP,
    const float* __restrict__ bqs, const float* __restrict__ bk,
    ushort* __restrict__ qpack, ushort* __restrict__ kpack, ushort* __restrict__ vpack)
{
    int lane = threadIdx.x & 63, wvi = threadIdx.x >> 6;
    int hi = lane >> 5;
    int t = blockIdx.x * 4 + wvi;
    if (t >= T_ALL) return;

    if (t < T_Q) {                               // q: rows 32*mb, cols 32*nc of [128x9216]
        int mb = t / NQC, nc = t - mb * NQC;
        const ushort* A = wqP + ((size_t)(mb * KSTEPS) * 64 + lane) * 8;
        const ushort* B = xbP + ((size_t)(nc * KSTEPS) * 64 + lane) * 8;
        f32x16 acc = mfma_loop(A, B);
        #pragma unroll
        for (int r = 0; r < 16; ++r)
            acc[r] += bqs[mb * 32 + (r & 3) + 8 * (r >> 2) + 4 * hi];
        short8v F1, F2;
        xform(acc, hi, F1, F2);
        *(short8v*)&qpack[((size_t)((2 * mb)     * NQC + nc) * 64 + lane) * 8] = F1;
        *(short8v*)&qpack[((size_t)((2 * mb + 1) * NQC + nc) * 64 + lane) * 8] = F2;
    } else if (t < T_K) {                        // k: [128x2304]
        int t2 = t - T_Q;
        int mb = t2 / NKC, nc = t2 - mb * NKC;
        const ushort* A = wkP  + ((size_t)(mb * KSTEPS) * 64 + lane) * 8;
        const ushort* B = xpbP + ((size_t)(nc * KSTEPS) * 64 + lane) * 8;
        f32x16 acc = mfma_loop(A, B);
        #pragma unroll
        for (int r = 0; r < 16; ++r)
            acc[r] += bk[mb * 32 + (r & 3) + 8 * (r >> 2) + 4 * hi];
        short8v F1, F2;
        xform(acc, hi, F1, F2);
        *(short8v*)&kpack[((size_t)((2 * mb)     * NKC + nc) * 64 + lane) * 8] = F1;
        *(short8v*)&kpack[((size_t)((2 * mb + 1) * NKC + nc) * 64 + lane) * 8] = F2;
    } else {                                     // v, transposed: C^T[key][c]
        int t3 = t - T_K;
        int cb = t3 / NKC, kc = t3 - cb * NKC;
        const ushort* A = xpbP + ((size_t)(kc * KSTEPS) * 64 + lane) * 8;
        const ushort* B = wvP  + ((size_t)(cb * KSTEPS) * 64 + lane) * 8;
        f32x16 acc = mfma_loop(A, B);
        short8v F1, F2;
        xform(acc, hi, F1, F2);
        *(short8v*)&vpack[((size_t)((cb * NKC + kc) * 2 + 0) * 64 + lane) * 8] = F1;
        *(short8v*)&vpack[((size_t)((cb * NKC + kc) * 2 + 1) * 64 + lane) * 8] = F2;
    }
}

// ---------------- fused attention: 64 queries/wave, 4-way key split ----------------
__global__ __launch_bounds__(256, 4) void attn_kernel(const ushort* __restrict__ qpack,
                                                      const ushort* __restrict__ kpack,
                                                      const ushort* __restrict__ vpack,
                                                      const float* __restrict__ x,
                                                      float* __restrict__ out) {
    __shared__ float part[4][2][64][20];   // [wave][qfrag][lane][16 o + rsum + pad] = 40 KB
    const int h = blockIdx.y;
    const int tid = threadIdx.x, lane = tid & 63;
    const int kh = tid >> 6;               // key quarter 0..3
    const int q31 = lane & 31, hi = lane >> 5;
    const int qp = blockIdx.x;

    short8v qf0 = *(const short8v*)&qpack[((size_t)(h * NQC + 2 * qp)     * 64 + lane) * 8];
    short8v qf1 = *(const short8v*)&qpack[((size_t)(h * NQC + 2 * qp + 1) * 64 + lane) * 8];

    const ushort* kp = kpack + ((size_t)(h * NKC + kh * KQRT) * 64 + lane) * 8;
    const ushort* vp = vpack + ((size_t)(h * NKC + kh * KQRT) * 2 * 64 + lane) * 8;

    short8v kf = *(const short8v*)kp;
    short8v v0 = *(const short8v*)vp;
    short8v v1 = *(const short8v*)(vp + 512);

    f32x16 o0, o1, zc;
    #pragma unroll
    for (int r = 0; r < 16; ++r) { o0[r] = 0.0f; o1[r] = 0.0f; zc[r] = 0.0f; }
    float rs0 = 0.0f, rs1 = 0.0f;

    for (int c = 0; c < KQRT; ++c) {
        short8v kcur = kf, v0c = v0, v1c = v1;
        int cn = (c == KQRT - 1) ? 0 : (c + 1);      // wrap: in-bounds, data unused
        kf = *(const short8v*)(kp + (size_t)cn * 512);
        v0 = *(const short8v*)(vp + (size_t)cn * 1024);
        v1 = *(const short8v*)(vp + (size_t)cn * 1024 + 512);

        // q-frag 0
        {
            f32x16 s = __builtin_amdgcn_mfma_f32_32x32x16_bf16(kcur, qf0, zc, 0, 0, 0);
            float e[16];
            #pragma unroll
            for (int r = 0; r < 16; ++r) e[r] = fexp2(s[r]);
            float t0 = 0.0f;
            #pragma unroll
            for (int r = 0; r < 16; ++r) t0 += e[r];
            rs0 += t0;
            uint a0 = cvtpk(e[0],  e[1]),  a1 = cvtpk(e[2],  e[3]);
            uint b0 = cvtpk(e[4],  e[5]),  b1 = cvtpk(e[6],  e[7]);
            uint a2 = cvtpk(e[8],  e[9]),  a3 = cvtpk(e[10], e[11]);
            uint b2 = cvtpk(e[12], e[13]), b3 = cvtpk(e[14], e[15]);
            B8u B1, B2;
            lswap(a0, b0, B1.u[0], B1.u[2], hi);
            lswap(a1, b1, B1.u[1], B1.u[3], hi);
            lswap(a2, b2, B2.u[0], B2.u[2], hi);
            lswap(a3, b3, B2.u[1], B2.u[3], hi);
            o0 = __builtin_amdgcn_mfma_f32_32x32x16_bf16(v0c, B1.v, o0, 0, 0, 0);
            o0 = __builtin_amdgcn_mfma_f32_32x32x16_bf16(v1c, B2.v, o0, 0, 0, 0);
        }
        // q-frag 1
        {
            f32x16 s = __builtin_amdgcn_mfma_f32_32x32x16_bf16(kcur, qf1, zc, 0, 0, 0);
            float e[16];
            #pragma unroll
            for (int r = 0; r < 16; ++r) e[r] = fexp2(s[r]);
            float t0 = 0.0f;
            #pragma unroll
            for (int r = 0; r < 16; ++r) t0 += e[r];
            rs1 += t0;
            uint a0 = cvtpk(e[0],  e[1]),  a1 = cvtpk(e[2],  e[3]);
            uint b0 = cvtpk(e[4],  e[5]),  b1 = cvtpk(e[6],  e[7]);
            uint a2 = cvtpk(e[8],  e[9]),  a3 = cvtpk(e[10], e[11]);
            uint b2 = cvtpk(e[12], e[13]), b3 = cvtpk(e[14], e[15]);
            B8u B1, B2;
            lswap(a0, b0, B1.u[0], B1.u[2], hi);
            lswap(a1, b1, B1.u[1], B1.u[3], hi);
            lswap(a2, b2, B2.u[0], B2.u[2], hi);
            lswap(a3, b3, B2.u[1], B2.u[3], hi);
            o1 = __builtin_amdgcn_mfma_f32_32x32x16_bf16(v0c, B1.v, o1, 0, 0, 0);
            o1 = __builtin_amdgcn_mfma_f32_32x32x16_bf16(v1c, B2.v, o1, 0, 0, 0);
        }
    }

    rs0 += __shfl_xor(rs0, 32);
    rs1 += __shfl_xor(rs1, 32);

    // write partials (both q-frags)
    {
        float* p0 = &part[kh][0][lane][0];
        #pragma unroll
        for (int i = 0; i < 4; ++i)
            *(float4*)&p0[4 * i] = *(float4*)((const float*)&o0 + 4 * i);
        p0[16] = rs0;
        float* p1 = &part[kh][1][lane][0];
        #pragma unroll
        for (int i = 0; i < 4; ++i)
            *(float4*)&p1[4 * i] = *(float4*)((const float*)&o1 + 4 * i);
        p1[16] = rs1;
    }
    __syncthreads();

    if (kh < 2) {   // wave kh combines q-frag kh
        float o[16] = {};
        float rs = 0.0f;
        #pragma unroll
        for (int w = 0; w < 4; ++w) {
            const float* pw = &part[w][kh][lane][0];
            #pragma unroll
            for (int i = 0; i < 4; ++i) {
                float4 f = *(const float4*)&pw[4 * i];
                o[4 * i + 0] += f.x; o[4 * i + 1] += f.y;
                o[4 * i + 2] += f.z; o[4 * i + 3] += f.w;
            }
            rs += pw[16];
        }
        float inv = 1.0f / rs;
        int q = (2 * qp + kh) * 32 + q31;
        #pragma unroll
        for (int r = 0; r < 16; ++r) {
            int dv = (r & 3) + 8 * (r >> 2) + 4 * hi;
            size_t i0 = (size_t)(h * DV + dv) * NQ + q;
            out[i0] = o[r] * inv + x[i0];
        }
    }
}

// ---------------- launcher ----------------
extern "C" void kernel_launch(void* const* d_in, const int* in_sizes, int n_in,
                              void* d_out, int out_size, void* d_ws, size_t ws_size,
                              hipStream_t stream) {
    const float* x  = (const float*)d_in[0];
    const float* wq = (const float*)d_in[1];
    const float* bq = (const float*)d_in[2];
    const float* wk = (const float*)d_in[3];
    const float* bk = (const float*)d_in[4];
    const float* wv = (const float*)d_in[5];
    float* out = (float*)d_out;

    ushort* p = (ushort*)d_ws;
    ushort* xbP   = p;  p += (size_t)U_XB  * 8;
    ushort* xpbP  = p;  p += (size_t)U_XPB * 8;
    ushort* wqP   = p;  p += (size_t)U_WQ  * 8;
    ushort* wkP   = p;  p += (size_t)U_WK  * 8;
    ushort* wvP   = p;  p += (size_t)U_WV  * 8;
    ushort* qpack = p;  p += (size_t)NH * NQC * 64 * 8;
    ushort* kpack = p;  p += (size_t)NH * NKC * 64 * 8;
    ushort* vpack = p;  p += (size_t)NH * NKC * 2 * 64 * 8;
    float*  bqs   = (float*)p;

    prep_kernel<<<(U_TOT + 255) / 256, 256, 0, stream>>>(x, wq, bq, wk, wv,
                                                         xbP, xpbP, wqP, wkP, wvP, bqs);
    gemm_fused<<<(T_ALL + 3) / 4, 256, 0, stream>>>(xbP, xpbP, wqP, wkP, wvP,
                                                    bqs, bk, qpack, kpack, vpack);
    attn_kernel<<<dim3(QPAIRS, NH), 256, 0, stream>>>(qpack, kpack, vpack, x, out);
}